// Round 1
// baseline (196.165 us; speedup 1.0000x reference)
//
#include <hip/hip_runtime.h>
#include <hip/hip_bf16.h>
#include <stdint.h>

typedef __bf16 bf16_t;
typedef __bf16 bf16x8 __attribute__((ext_vector_type(8)));
typedef float f32x4 __attribute__((ext_vector_type(4)));

#define DEVI __device__ __forceinline__

constexpr int BB = 2;       // batch
constexpr int SS = 4096;    // seq
constexpr int EE = 1024;    // embed
constexpr int HH = 16;      // heads
constexpr int DD = 64;      // head dim
constexpr int MM = BB * SS; // 8192 token rows

// async global->LDS, 16B per lane; LDS dest must be wave-uniform base (HW adds lane*16)
DEVI void gload16(const void* g, void* l) {
  __builtin_amdgcn_global_load_lds(
      (const __attribute__((address_space(1))) void*)g,
      (__attribute__((address_space(3))) void*)l, 16, 0, 0);
}

// ---------------- f32 -> bf16 convert (vectorized 8/thread) ----------------
__global__ void cvt_kernel(const float* __restrict__ in, bf16_t* __restrict__ out, int n8) {
  int i = blockIdx.x * 256 + threadIdx.x;
  if (i >= n8) return;
  const float* p = in + (size_t)i * 8;
  bf16x8 o;
#pragma unroll
  for (int j = 0; j < 8; ++j) o[j] = (bf16_t)p[j];
  *(bf16x8*)(out + (size_t)i * 8) = o;
}

// ---------------- weight transpose + cvt: W[k][n] f32 -> WT[n][k] bf16 ----------------
__global__ void wt_kernel(const float* __restrict__ w0, const float* __restrict__ w1,
                          const float* __restrict__ w2, const float* __restrict__ w3,
                          const float* __restrict__ w4, bf16_t* __restrict__ out) {
  __shared__ float tile[32][33];
  const float* Wsel = blockIdx.z == 0 ? w0 : blockIdx.z == 1 ? w1 :
                      blockIdx.z == 2 ? w2 : blockIdx.z == 3 ? w3 : w4;
  bf16_t* O = out + (size_t)blockIdx.z * EE * EE;
  int n0 = blockIdx.x * 32, k0 = blockIdx.y * 32;
  int tx = threadIdx.x & 31, ty = threadIdx.x >> 5;
#pragma unroll
  for (int i = 0; i < 4; ++i)
    tile[ty + i * 8][tx] = Wsel[(size_t)(k0 + ty + i * 8) * EE + n0 + tx];
  __syncthreads();
#pragma unroll
  for (int i = 0; i < 4; ++i)
    O[(size_t)(n0 + ty + i * 8) * EE + k0 + tx] = (bf16_t)tile[tx][ty + i * 8];
}

// ---------------- GEMM: C[M][N] = A[M][K] @ Bt[N][K]^T, 128x128 tile, BK=64 ----------------
// MODE 0: bf16 out into 4 contiguous 16MB regions (Q,K,Vt,G); V (widx==2) written transposed [B][H][D][S]
// MODE 1: f32 out [M][1024]
template <int MODE>
__global__ __launch_bounds__(256) void gemm_bt(const bf16_t* __restrict__ A,
                                               const bf16_t* __restrict__ Bt,
                                               void* __restrict__ Cout, int Kdim) {
  __shared__ bf16_t Al[128 * 64];
  __shared__ bf16_t Bl[128 * 64];
  const int m0 = blockIdx.x * 128;
  const int n0 = blockIdx.y * 128;
  const int tid = threadIdx.x;
  const int wv = tid >> 6, ln = tid & 63;
  const int wm = wv >> 1, wn = wv & 1;
  f32x4 acc[4][4] = {};

  for (int k0 = 0; k0 < Kdim; k0 += 64) {
    __syncthreads();  // prior iter's LDS readers done before overwrite
#pragma unroll
    for (int i = 0; i < 4; ++i) {
      int slot = i * 256 + wv * 64 + ln;  // 16B slots, 8 per 128B row
      int r = slot >> 3, c = slot & 7;
      int cs = c ^ (r & 7);  // inverse-swizzled source chunk (linear LDS dest)
      gload16(A + (size_t)(m0 + r) * Kdim + k0 + cs * 8, Al + (size_t)(i * 256 + wv * 64) * 8);
      gload16(Bt + (size_t)(n0 + r) * Kdim + k0 + cs * 8, Bl + (size_t)(i * 256 + wv * 64) * 8);
    }
    __syncthreads();  // compiler drains vmcnt(0) before barrier
#pragma unroll
    for (int kk = 0; kk < 2; ++kk) {
      bf16x8 af[4], bfr[4];
#pragma unroll
      for (int mi = 0; mi < 4; ++mi) {
        int row = wm * 64 + mi * 16 + (ln & 15);
        int ch = (kk * 4 + (ln >> 4)) ^ (row & 7);
        af[mi] = *(const bf16x8*)(Al + row * 64 + ch * 8);
      }
#pragma unroll
      for (int ni = 0; ni < 4; ++ni) {
        int row = wn * 64 + ni * 16 + (ln & 15);
        int ch = (kk * 4 + (ln >> 4)) ^ (row & 7);
        bfr[ni] = *(const bf16x8*)(Bl + row * 64 + ch * 8);
      }
#pragma unroll
      for (int mi = 0; mi < 4; ++mi)
#pragma unroll
        for (int ni = 0; ni < 4; ++ni)
          acc[mi][ni] = __builtin_amdgcn_mfma_f32_16x16x32_bf16(af[mi], bfr[ni], acc[mi][ni], 0, 0, 0);
    }
  }

  if (MODE == 0) {
    bf16_t* Obase = (bf16_t*)Cout;
#pragma unroll
    for (int mi = 0; mi < 4; ++mi) {
#pragma unroll
      for (int ni = 0; ni < 4; ++ni) {
        int row = m0 + wm * 64 + mi * 16 + ((ln >> 4) << 2);  // + reg
        int col = n0 + wn * 64 + ni * 16 + (ln & 15);
        int widx = col >> 10, ncol = col & 1023;
        bf16_t* W = Obase + (size_t)widx * MM * EE;
        if (widx == 2) {  // V: write transposed [B][H][D][S]
          int h = ncol >> 6, d = ncol & 63;
          int b = row >> 12, s = row & (SS - 1);
          bf16_t* p = W + (((size_t)b * HH + h) * DD + d) * SS + s;
#pragma unroll
          for (int r = 0; r < 4; ++r) p[r] = (bf16_t)acc[mi][ni][r];
        } else {
          bf16_t* p = W + (size_t)row * EE + ncol;
#pragma unroll
          for (int r = 0; r < 4; ++r) p[(size_t)r * EE] = (bf16_t)acc[mi][ni][r];
        }
      }
    }
  } else {
    float* O = (float*)Cout;
#pragma unroll
    for (int mi = 0; mi < 4; ++mi)
#pragma unroll
      for (int ni = 0; ni < 4; ++ni) {
        int row = m0 + wm * 64 + mi * 16 + ((ln >> 4) << 2);
        int col = n0 + wn * 64 + ni * 16 + (ln & 15);
#pragma unroll
        for (int r = 0; r < 4; ++r) O[(size_t)(row + r) * EE + col] = acc[mi][ni][r];
      }
  }
}

// ---------------- RoPE in-place on Q and K (bf16), cos/sin f32 [S][64] ----------------
__global__ void rope_kernel(bf16_t* __restrict__ Q, bf16_t* __restrict__ Kt,
                            const float* __restrict__ cosp, const float* __restrict__ sinp) {
  int idx = blockIdx.x * 256 + threadIdx.x;  // MM*HH*4 threads
  int dg = (idx & 3) * 8;
  int h = (idx >> 2) & (HH - 1);
  int m = idx >> 6;
  if (m >= MM) return;
  int s = m & (SS - 1);
  size_t base = (size_t)m * EE + h * DD;
  float cl[8], sl[8], chv[8], shv[8];
#pragma unroll
  for (int j = 0; j < 8; ++j) {
    cl[j] = cosp[s * DD + dg + j];
    sl[j] = sinp[s * DD + dg + j];
    chv[j] = cosp[s * DD + 32 + dg + j];
    shv[j] = sinp[s * DD + 32 + dg + j];
  }
#pragma unroll
  for (int t = 0; t < 2; ++t) {
    bf16_t* P = t == 0 ? Q : Kt;
    bf16x8 lo = *(bf16x8*)(P + base + dg);
    bf16x8 hi = *(bf16x8*)(P + base + 32 + dg);
    bf16x8 olo, ohi;
#pragma unroll
    for (int j = 0; j < 8; ++j) {
      float ql = (float)lo[j], qh = (float)hi[j];
      olo[j] = (bf16_t)(ql * cl[j] - qh * sl[j]);
      ohi[j] = (bf16_t)(qh * chv[j] + ql * shv[j]);
    }
    *(bf16x8*)(P + base + dg) = olo;
    *(bf16x8*)(P + base + 32 + dg) = ohi;
  }
}

// ---------------- block-diagonal attention ----------------
// grid: B*nb*H blocks; block: 4 waves, wave handles 64 q-rows of the 256-row block.
__global__ __launch_bounds__(256) void attn_kernel(const bf16_t* __restrict__ Q,
                                                   const bf16_t* __restrict__ Kc,
                                                   const bf16_t* __restrict__ Vt,
                                                   bf16_t* __restrict__ AO) {
  __shared__ bf16_t Kl[64 * 64];
  __shared__ bf16_t Vl[64 * 64];
  __shared__ bf16_t Pl[4][64 * 64];
  const int bx = blockIdx.x;
  const int h = bx & 15, sb = (bx >> 4) & 15, b = bx >> 8;
  const int tid = threadIdx.x, wv = tid >> 6, ln = tid & 63;
  const int qrow0 = b * SS + sb * 256 + wv * 64;

  // Q fragments straight from global (RoPE'd)
  bf16x8 qf[4][2];
#pragma unroll
  for (int mi = 0; mi < 4; ++mi)
#pragma unroll
    for (int kk = 0; kk < 2; ++kk)
      qf[mi][kk] = *(const bf16x8*)(Q + (size_t)(qrow0 + mi * 16 + (ln & 15)) * EE +
                                    h * DD + kk * 32 + ((ln >> 4) << 3));

  f32x4 o[4][4] = {};
  float mr[4][4], lr[4][4];
#pragma unroll
  for (int i = 0; i < 4; ++i)
#pragma unroll
    for (int r = 0; r < 4; ++r) { mr[i][r] = -1e30f; lr[i][r] = 0.f; }

  for (int kc = 0; kc < 4; ++kc) {
    __syncthreads();
    const int krow0 = b * SS + sb * 256 + kc * 64;
#pragma unroll
    for (int i = 0; i < 2; ++i) {
      int slot = i * 256 + wv * 64 + ln;
      int r = slot >> 3, c = slot & 7, cs = c ^ (r & 7);
      gload16(Kc + (size_t)(krow0 + r) * EE + h * DD + cs * 8, Kl + (i * 256 + wv * 64) * 8);
      gload16(Vt + (((size_t)b * HH + h) * DD + r) * SS + sb * 256 + kc * 64 + cs * 8,
              Vl + (i * 256 + wv * 64) * 8);
    }
    __syncthreads();

    // scores: S[64q][64k] per wave
    f32x4 sc[4][4] = {};
#pragma unroll
    for (int kk = 0; kk < 2; ++kk) {
      bf16x8 kf[4];
#pragma unroll
      for (int ni = 0; ni < 4; ++ni) {
        int row = ni * 16 + (ln & 15);
        int ch = (kk * 4 + (ln >> 4)) ^ (row & 7);
        kf[ni] = *(const bf16x8*)(Kl + row * 64 + ch * 8);
      }
#pragma unroll
      for (int mi = 0; mi < 4; ++mi)
#pragma unroll
        for (int ni = 0; ni < 4; ++ni)
          sc[mi][ni] = __builtin_amdgcn_mfma_f32_16x16x32_bf16(qf[mi][kk], kf[ni], sc[mi][ni], 0, 0, 0);
    }
#pragma unroll
    for (int mi = 0; mi < 4; ++mi)
#pragma unroll
      for (int ni = 0; ni < 4; ++ni) sc[mi][ni] *= 0.125f;  // 1/sqrt(64)

    // online softmax; row = (ln>>4)*4 + reg, cols spread over ln&15 and ni
#pragma unroll
    for (int mi = 0; mi < 4; ++mi) {
#pragma unroll
      for (int r = 0; r < 4; ++r) {
        float mx = fmaxf(fmaxf(sc[mi][0][r], sc[mi][1][r]), fmaxf(sc[mi][2][r], sc[mi][3][r]));
#pragma unroll
        for (int d = 1; d < 16; d <<= 1) mx = fmaxf(mx, __shfl_xor(mx, d));
        float mn = fmaxf(mr[mi][r], mx);
        float scal = __expf(mr[mi][r] - mn);
        mr[mi][r] = mn;
        float rs = 0.f;
#pragma unroll
        for (int ni = 0; ni < 4; ++ni) {
          float p = __expf(sc[mi][ni][r] - mn);
          sc[mi][ni][r] = p;
          rs += p;
        }
#pragma unroll
        for (int d = 1; d < 16; d <<= 1) rs += __shfl_xor(rs, d);
        lr[mi][r] = lr[mi][r] * scal + rs;
#pragma unroll
        for (int nd = 0; nd < 4; ++nd) o[mi][nd][r] *= scal;
      }
    }

    // P -> per-wave LDS (swizzled), then PV
    bf16_t* P = Pl[wv];
#pragma unroll
    for (int mi = 0; mi < 4; ++mi)
#pragma unroll
      for (int ni = 0; ni < 4; ++ni)
#pragma unroll
        for (int r = 0; r < 4; ++r) {
          int row = mi * 16 + ((ln >> 4) << 2) + r;
          int col = ni * 16 + (ln & 15);
          P[row * 64 + (col ^ ((row & 7) << 3))] = (bf16_t)sc[mi][ni][r];
        }
#pragma unroll
    for (int kk = 0; kk < 2; ++kk) {
      bf16x8 pf[4], vf[4];
#pragma unroll
      for (int mi = 0; mi < 4; ++mi) {
        int row = mi * 16 + (ln & 15);
        int ch = (kk * 4 + (ln >> 4)) ^ (row & 7);
        pf[mi] = *(const bf16x8*)(P + row * 64 + ch * 8);
      }
#pragma unroll
      for (int nd = 0; nd < 4; ++nd) {
        int row = nd * 16 + (ln & 15);
        int ch = (kk * 4 + (ln >> 4)) ^ (row & 7);
        vf[nd] = *(const bf16x8*)(Vl + row * 64 + ch * 8);
      }
#pragma unroll
      for (int mi = 0; mi < 4; ++mi)
#pragma unroll
        for (int nd = 0; nd < 4; ++nd)
          o[mi][nd] = __builtin_amdgcn_mfma_f32_16x16x32_bf16(pf[mi], vf[nd], o[mi][nd], 0, 0, 0);
    }
  }

#pragma unroll
  for (int mi = 0; mi < 4; ++mi)
#pragma unroll
    for (int nd = 0; nd < 4; ++nd)
#pragma unroll
      for (int r = 0; r < 4; ++r) {
        int m = qrow0 + mi * 16 + ((ln >> 4) << 2) + r;
        int col = h * DD + nd * 16 + (ln & 15);
        AO[(size_t)m * EE + col] = (bf16_t)(o[mi][nd][r] / lr[mi][r]);
      }
}

// ---------------- gate: U = AO * sigmoid(G) ----------------
__global__ void gate_kernel(const bf16_t* __restrict__ AO, const bf16_t* __restrict__ G,
                            bf16_t* __restrict__ U, int n8) {
  int i = blockIdx.x * 256 + threadIdx.x;
  if (i >= n8) return;
  bf16x8 a = *(const bf16x8*)(AO + (size_t)i * 8);
  bf16x8 g = *(const bf16x8*)(G + (size_t)i * 8);
  bf16x8 u;
#pragma unroll
  for (int j = 0; j < 8; ++j) {
    float av = (float)a[j], gv = (float)g[j];
    u[j] = (bf16_t)(av / (1.f + __expf(-gv)));
  }
  *(bf16x8*)(U + (size_t)i * 8) = u;
}

extern "C" void kernel_launch(void* const* d_in, const int* in_sizes, int n_in,
                              void* d_out, int out_size, void* d_ws, size_t ws_size,
                              hipStream_t stream) {
  const float* x = (const float*)d_in[0];
  const float* Wq = (const float*)d_in[1];
  const float* Wk = (const float*)d_in[2];
  const float* Wv = (const float*)d_in[3];
  const float* Wg = (const float*)d_in[4];
  const float* Wo = (const float*)d_in[5];
  const float* cosp = (const float*)d_in[6];
  const float* sinp = (const float*)d_in[7];
  float* out = (float*)d_out;

  char* ws = (char*)d_ws;
  bf16_t* XB = (bf16_t*)(ws);                       // 16MB: x bf16; reused as AO after QKVG GEMM
  bf16_t* WT = (bf16_t*)(ws + (16ll << 20));        // 10MB: [5][1024][1024] W^T bf16 (q,k,v,g,o)
  bf16_t* QB = (bf16_t*)(ws + (26ll << 20));        // 16MB: Q; reused as U after attention
  bf16_t* KB = (bf16_t*)(ws + (42ll << 20));        // 16MB: K
  bf16_t* VT = (bf16_t*)(ws + (58ll << 20));        // 16MB: V transposed [B][H][D][S]
  bf16_t* GB = (bf16_t*)(ws + (74ll << 20));        // 16MB: gate
  bf16_t* AO = XB;                                  // attention output reuses XB region

  const int n8 = MM * EE / 8;  // 1048576
  cvt_kernel<<<n8 / 256, 256, 0, stream>>>(x, XB, n8);
  wt_kernel<<<dim3(32, 32, 5), 256, 0, stream>>>(Wq, Wk, Wv, Wg, Wo, WT);
  // Q,K,Vt,G are the 4 contiguous 16MB regions starting at QB (stride MM*EE elements)
  gemm_bt<0><<<dim3(MM / 128, 4 * EE / 128), 256, 0, stream>>>(XB, WT, QB, EE);
  rope_kernel<<<(MM * HH * 4) / 256, 256, 0, stream>>>(QB, KB, cosp, sinp);
  attn_kernel<<<BB * (SS / 256) * HH, 256, 0, stream>>>(QB, KB, VT, AO);
  gate_kernel<<<n8 / 256, 256, 0, stream>>>(AO, GB, QB, n8);
  gemm_bt<1><<<dim3(MM / 128, EE / 128), 256, 0, stream>>>(QB, WT + (size_t)4 * EE * EE, out, EE);
}